// Round 6
// baseline (80.835 us; speedup 1.0000x reference)
//
#include <hip/hip_runtime.h>

#define NUM_INPUTS 4096
#define NUM_LEAVES 2048
#define R_PB 8
#define BLK 256

typedef const __attribute__((address_space(1))) void* gas_ptr;
typedef __attribute__((address_space(3))) void* las_ptr;
typedef float vfloat4 __attribute__((ext_vector_type(4)));

// out[b, l] = x[b, idx[l]]
// R1's occupancy (32 KiB LDS, 20 waves/CU) + R2's counted-vmcnt pipeline:
// 4-wave block, 2x16KiB row double-buffer, raw s_barrier with per-wave
// COUNTED vmcnt (never a full drain in steady state) so the next row's
// global_load_lds stay in flight across each gather+store phase.
__global__ __launch_bounds__(BLK) void FrozenInputToLeaf_pipe(
    const float* __restrict__ x,
    const int* __restrict__ idx,
    float* __restrict__ out) {
    __shared__ float buf[2][NUM_INPUTS];  // 32 KiB -> 5 blocks/CU

    const int t = threadIdx.x;
    const size_t row0 = (size_t)blockIdx.x * R_PB;

    // Indices once per block (8 KiB, L2-hot).
    const int4* __restrict__ iv = (const int4*)idx;
    const int4 i0 = iv[t * 2 + 0];
    const int4 i1 = iv[t * 2 + 1];

    // Prologue: stage row0 -> buf[0]. 4 gload_lds x 16B per thread.
    {
        const float* __restrict__ src = x + row0 * NUM_INPUTS;
#pragma unroll
        for (int j = 0; j < 4; ++j) {
            const int e = (j * BLK + t) * 4;
            __builtin_amdgcn_global_load_lds((gas_ptr)(src + e),
                                             (las_ptr)(&buf[0][e]), 16, 0, 0);
        }
    }

#pragma unroll
    for (int r = 0; r < R_PB; ++r) {
        const int p = r & 1;  // compile-time after unroll
        if (r + 1 < R_PB) {
            // Issue next row's loads into the other buffer BEFORE waiting.
            // Safe: buf[p^1]'s previous row was fully gathered before the
            // trailing barrier of iter r-1.
            const float* __restrict__ src = x + (row0 + r + 1) * NUM_INPUTS;
#pragma unroll
            for (int j = 0; j < 4; ++j) {
                const int e = (j * BLK + t) * 4;
                __builtin_amdgcn_global_load_lds((gas_ptr)(src + e),
                                                 (las_ptr)(&buf[p ^ 1][e]), 16, 0, 0);
            }
        }
        // Per-wave counted wait: retire exactly this row's 4 loads.
        // FIFO: r=0: [loads0:4][loads1:4] -> vmcnt(4)
        //       steady: [loads r:4][stores r-1:2][loads r+1:4] -> vmcnt(6)
        //       last:  [loads R-1:4][stores R-2:2] -> vmcnt(2)
        if (r == 0)             asm volatile("s_waitcnt vmcnt(4)" ::: "memory");
        else if (r + 1 < R_PB)  asm volatile("s_waitcnt vmcnt(6)" ::: "memory");
        else                    asm volatile("s_waitcnt vmcnt(2)" ::: "memory");
        __builtin_amdgcn_sched_barrier(0);
        __builtin_amdgcn_s_barrier();  // all waves' row-r loads have landed

        const float* __restrict__ cur = buf[p];
        vfloat4 o0, o1;
        o0.x = cur[i0.x];
        o0.y = cur[i0.y];
        o0.z = cur[i0.z];
        o0.w = cur[i0.w];
        o1.x = cur[i1.x];
        o1.y = cur[i1.y];
        o1.z = cur[i1.z];
        o1.w = cur[i1.w];

        vfloat4* __restrict__ ov = (vfloat4*)(out + (row0 + r) * NUM_LEAVES);
        ov[t * 2 + 0] = o0;
        ov[t * 2 + 1] = o1;

        // This wave's ds_reads were consumed before the stores issued; drain
        // lgkm defensively, then cross-wave sync so next iter's loads may
        // overwrite buf[p].
        asm volatile("s_waitcnt lgkmcnt(0)" ::: "memory");
        __builtin_amdgcn_sched_barrier(0);
        __builtin_amdgcn_s_barrier();
    }
}

extern "C" void kernel_launch(void* const* d_in, const int* in_sizes, int n_in,
                              void* d_out, int out_size, void* d_ws, size_t ws_size,
                              hipStream_t stream) {
    const float* x = (const float*)d_in[0];
    const int* idx = (const int*)d_in[1];
    float* out = (float*)d_out;

    const int batch = in_sizes[0] / NUM_INPUTS;  // 16384
    const int grid = batch / R_PB;               // 2048

    FrozenInputToLeaf_pipe<<<grid, BLK, 0, stream>>>(x, idx, out);
}